// Round 2
// baseline (333.395 us; speedup 1.0000x reference)
//
#include <hip/hip_runtime.h>
#include <math.h>

#define CDIM 8
#define CSZ  4096
#define NB   8
#define ND   1024
#define NT   4096
#define NFR  (NB * NT)            // 32768 frames
#define TAU  1e-4f                // f32-vs-f64 safety gap (f32 sim err <= ~1e-6)

// ---- d_out layout (flat f32, return order) ----
static constexpr size_t CL_OFF  = (size_t)NB * ND * NT;
static constexpr size_t CBL_OFF = CL_OFF + NB;
static constexpr size_t IDX_OFF = CBL_OFF + NB;
static constexpr size_t LAT_OFF = IDX_OFF + (size_t)NB * NT;

// ---- d_ws layout (byte offsets) ----
static constexpr size_t WT_B     = 0;                          // f64[16384] transposed in-proj weights
static constexpr size_t CBN64A_B = 131072;                     // f64[4096*8] normalized cb_a
static constexpr size_t CBN64B_B = CBN64A_B + 262144;          // f64[4096*8] normalized cb_b
static constexpr size_t CBN32A_B = CBN64B_B + 262144;          // f32[4096*8]
static constexpr size_t CBN32B_B = CBN32A_B + 131072;          // f32[4096*8]
static constexpr size_t ZA_B     = CBN32B_B + 131072;          // f64[NFR*16] projections
static constexpr size_t E32_B    = ZA_B + (size_t)NFR * 16 * 8;// f32[NFR*16] normalized enc
static constexpr size_t BESTV_B  = E32_B + (size_t)NFR * 16 * 4;   // f32[4 * 262144] b1A,b2A,b1B,b2B
static constexpr size_t BESTI_B  = BESTV_B + 4ull * 262144 * 4;    // i32[2 * 262144] iA,iB
static constexpr size_t PART_B   = BESTI_B + 2ull * 262144 * 4;    // f64[512] loss partials
static constexpr size_t WS_NEED  = PART_B + 512 * 8;
#define NSLOT 262144   // 512 framegroups * 8 slices * 64 lanes

// ================= prep: transposed f64 weights + normalized codebooks =================
__global__ void vq_prep(const float* __restrict__ w_in_a, const float* __restrict__ w_in_b,
                        const float* __restrict__ cb_a,  const float* __restrict__ cb_b,
                        double* __restrict__ wT,
                        double* __restrict__ cbn64A, double* __restrict__ cbn64B,
                        float* __restrict__ cbn32A,  float* __restrict__ cbn32B) {
    int id = blockIdx.x * 256 + threadIdx.x;
    if (id < 16384) {
        int i = id >> 4, o = id & 15;
        float w = (o < 8) ? w_in_a[o * ND + i] : w_in_b[(o - 8) * ND + i];
        wT[id] = (double)w;
    } else if (id < 16384 + 2 * CSZ) {
        int e = id - 16384;
        int book = e >> 12, j = e & (CSZ - 1);
        const float* src = (book ? cb_b : cb_a) + (size_t)j * CDIM;
        double* d64 = (book ? cbn64B : cbn64A) + (size_t)j * CDIM;
        float*  d32 = (book ? cbn32B : cbn32A) + (size_t)j * CDIM;
        double c[CDIM]; double n2 = 0.0;
#pragma unroll
        for (int k = 0; k < CDIM; ++k) { c[k] = (double)src[k]; n2 = fma(c[k], c[k], n2); }
        double den = fmax(sqrt(n2), 1e-12);
#pragma unroll
        for (int k = 0; k < CDIM; ++k) { double v = c[k] / den; d64[k] = v; d32[k] = (float)v; }
    }
}

// ================= A: projection + normalize (f64), 512 blocks x 512 thr =================
__global__ void __launch_bounds__(512, 4)
vq_proj(const float* __restrict__ z,
        const float* __restrict__ b_in_a, const float* __restrict__ b_in_b,
        const double* __restrict__ wT,
        double* __restrict__ za, float* __restrict__ e32,
        float* __restrict__ out) {
    const int tid  = threadIdx.x;
    const int lane = tid & 63;
    const int wave = __builtin_amdgcn_readfirstlane(tid >> 6);  // 0..7
    const int blk  = blockIdx.x;
    const int b    = blk >> 6;
    const int t    = ((blk & 63) << 6) + lane;
    const int f    = (blk << 6) + lane;                         // global frame id

    __shared__ double red[8][64][9];                            // 36.9 KB

    double acc[16];
#pragma unroll
    for (int k = 0; k < 16; ++k) acc[k] = 0.0;

    const float* zp = z + ((size_t)b * ND) * NT + t;
    const int i0 = wave * 128;
#pragma unroll 4
    for (int ii = 0; ii < 128; ++ii) {
        const int i = i0 + ii;
        const double zd = (double)zp[(size_t)i * NT];
        const double* wr = wT + (size_t)i * 16;                 // uniform -> s_load
#pragma unroll
        for (int k = 0; k < 16; ++k) acc[k] = fma(wr[k], zd, acc[k]);
    }

    double za16[16];
#pragma unroll
    for (int r = 0; r < 2; ++r) {
#pragma unroll
        for (int k = 0; k < 8; ++k) red[wave][lane][k] = acc[8 * r + k];
        __syncthreads();
        if (wave == 0) {
#pragma unroll
            for (int k = 0; k < 8; ++k) {
                double s = red[0][lane][k];
#pragma unroll
                for (int w = 1; w < 8; ++w) s += red[w][lane][k];
                za16[8 * r + k] = s;
            }
        }
        __syncthreads();
    }

    if (wave != 0) return;

#pragma unroll
    for (int k = 0; k < 8; ++k) { za16[k] += (double)b_in_a[k]; za16[8 + k] += (double)b_in_b[k]; }

    // latent output (f32)
#pragma unroll
    for (int k = 0; k < 16; ++k)
        out[LAT_OFF + ((size_t)b * 16 + k) * NT + t] = (float)za16[k];

    // store za (f64)
    double* zf = za + (size_t)f * 16;
#pragma unroll
    for (int k = 0; k < 16; ++k) zf[k] = za16[k];

    // normalize (f64) -> store e32 (f32)
    double n2a = 0.0, n2b = 0.0;
#pragma unroll
    for (int k = 0; k < 8; ++k) { n2a = fma(za16[k], za16[k], n2a); n2b = fma(za16[8+k], za16[8+k], n2b); }
    const double ia_ = 1.0 / fmax(sqrt(n2a), 1e-12);
    const double ib_ = 1.0 / fmax(sqrt(n2b), 1e-12);
    float* ef = e32 + (size_t)f * 16;
#pragma unroll
    for (int k = 0; k < 8; ++k) {
        ef[k]     = (float)(za16[k] * ia_);
        ef[8 + k] = (float)(za16[8 + k] * ib_);
    }
}

// ================= B: f32 prescan with best1/best2, 1024 blocks x 256 thr =================
__global__ void __launch_bounds__(256, 4)
vq_scan(const float* __restrict__ e32,
        const float* __restrict__ cbn32A, const float* __restrict__ cbn32B,
        float* __restrict__ bv, int* __restrict__ bi) {
    const int tid   = threadIdx.x;
    const int lane  = tid & 63;
    const int wave  = __builtin_amdgcn_readfirstlane(tid >> 6);  // 0..3
    const int fg    = blockIdx.x >> 1;
    const int slice = ((blockIdx.x & 1) << 2) + wave;            // 0..7
    const int f     = (fg << 6) + lane;
    const int j0    = slice << 9;                                // 512 entries per slice

    const float* ef = e32 + (size_t)f * 16;
    float ea[8], eb[8];
#pragma unroll
    for (int k = 0; k < 8; ++k) { ea[k] = ef[k]; eb[k] = ef[8 + k]; }

    float b1A = -1e30f, b2A = -1e30f, b1B = -1e30f, b2B = -1e30f;
    int iA = j0, iB = j0;

#pragma unroll 4
    for (int jj = 0; jj < 512; ++jj) {
        const int j = j0 + jj;
        const float* ca = cbn32A + (size_t)j * 8;               // uniform -> s_load
        const float* cb = cbn32B + (size_t)j * 8;
        float sA = ea[0] * ca[0], sB = eb[0] * cb[0];
#pragma unroll
        for (int k = 1; k < 8; ++k) { sA = fmaf(ea[k], ca[k], sA); sB = fmaf(eb[k], cb[k], sB); }
        // best2 then best1 (strict > keeps first occurrence)
        b2A = fmaxf(b2A, fminf(sA, b1A));
        if (sA > b1A) { b1A = sA; iA = j; }
        b2B = fmaxf(b2B, fminf(sB, b1B));
        if (sB > b1B) { b1B = sB; iB = j; }
    }

    const size_t o = ((size_t)(fg * 8 + slice)) * 64 + lane;
    bv[o]             = b1A;
    bv[NSLOT + o]     = b2A;
    bv[2 * NSLOT + o] = b1B;
    bv[3 * NSLOT + o] = b2B;
    bi[o]             = iA;
    bi[NSLOT + o]     = iB;
}

// ================= C: combine + gated f64 rescan + gather + out-proj + losses =================
__global__ void __launch_bounds__(256, 2)
vq_out(const float* __restrict__ bv, const int* __restrict__ bi,
       const double* __restrict__ za,
       const double* __restrict__ cbn64A, const double* __restrict__ cbn64B,
       const float* __restrict__ cb_a, const float* __restrict__ cb_b,
       const float* __restrict__ w_out_a, const float* __restrict__ b_out_a,
       const float* __restrict__ w_out_b, const float* __restrict__ b_out_b,
       float* __restrict__ out, double* __restrict__ part) {
    const int tid  = threadIdx.x;
    const int lane = tid & 63;
    const int wave = __builtin_amdgcn_readfirstlane(tid >> 6);
    const int fg   = blockIdx.x;
    const int b    = fg >> 6;
    const int t    = ((fg & 63) << 6) + lane;
    const int f    = (fg << 6) + lane;

    // ---- combine 8 slices (ascending -> first-occurrence preserved) ----
    float B1A = -1e30f, B2A = -1e30f, B1B = -1e30f, B2B = -1e30f;
    int iA = 0, iB = 0;
#pragma unroll
    for (int s = 0; s < 8; ++s) {
        const size_t o = ((size_t)(fg * 8 + s)) * 64 + lane;
        const float v1 = bv[o], v2 = bv[NSLOT + o];
        const int   j1 = bi[o];
        if (v1 > B1A) { B2A = fmaxf(B2A, B1A); B1A = v1; iA = j1; }
        else          { B2A = fmaxf(B2A, v1); }
        B2A = fmaxf(B2A, v2);
        const float w1 = bv[2 * NSLOT + o], w2 = bv[3 * NSLOT + o];
        const int   k1 = bi[NSLOT + o];
        if (w1 > B1B) { B2B = fmaxf(B2B, B1B); B1B = w1; iB = k1; }
        else          { B2B = fmaxf(B2B, w1); }
        B2B = fmaxf(B2B, w2);
    }

    // ---- gated exact f64 rescan for near-ties (rare) ----
    const bool need = ((B1A - B2A) < TAU) || ((B1B - B2B) < TAU);
    unsigned long long m = __ballot(need);
    while (m) {
        const int src = __ffsll(m) - 1; m &= (m - 1);
        const int fr = (fg << 6) + src;
        const double* zr = za + (size_t)fr * 16;                // uniform
        double zra[16];
#pragma unroll
        for (int k = 0; k < 16; ++k) zra[k] = zr[k];
        double n2a = 0.0, n2b = 0.0;
#pragma unroll
        for (int k = 0; k < 8; ++k) { n2a = fma(zra[k], zra[k], n2a); n2b = fma(zra[8+k], zra[8+k], n2b); }
        const double ja_ = 1.0 / fmax(sqrt(n2a), 1e-12);
        const double jb_ = 1.0 / fmax(sqrt(n2b), 1e-12);
        double ea64[8], eb64[8];
#pragma unroll
        for (int k = 0; k < 8; ++k) { ea64[k] = zra[k] * ja_; eb64[k] = zra[8 + k] * jb_; }

        double bvA = -1e300, bvB = -1e300; int biA = 0, biB = 0;
        for (int e = lane; e < CSZ; e += 64) {
            const double* ra = cbn64A + (size_t)e * 8;
            const double* rb = cbn64B + (size_t)e * 8;
            double sA = 0.0, sB = 0.0;
#pragma unroll
            for (int k = 0; k < 8; ++k) { sA = fma(ea64[k], ra[k], sA); sB = fma(eb64[k], rb[k], sB); }
            if (sA > bvA) { bvA = sA; biA = e; }
            if (sB > bvB) { bvB = sB; biB = e; }
        }
#pragma unroll
        for (int off = 32; off > 0; off >>= 1) {
            double ov = __shfl_xor(bvA, off); int oi = __shfl_xor(biA, off);
            if (ov > bvA || (ov == bvA && oi < biA)) { bvA = ov; biA = oi; }
            ov = __shfl_xor(bvB, off); oi = __shfl_xor(biB, off);
            if (ov > bvB || (ov == bvB && oi < biB)) { bvB = ov; biB = oi; }
        }
        if (lane == src) { iA = biA; iB = biB; }
    }

    // ---- gather raw codewords ----
    const float4 qa0 = *(const float4*)(cb_a + (size_t)iA * CDIM);
    const float4 qa1 = *(const float4*)(cb_a + (size_t)iA * CDIM + 4);
    const float4 qb0 = *(const float4*)(cb_b + (size_t)iB * CDIM);
    const float4 qb1 = *(const float4*)(cb_b + (size_t)iB * CDIM + 4);
    const float zaq[8] = {qa0.x, qa0.y, qa0.z, qa0.w, qa1.x, qa1.y, qa1.z, qa1.w};
    const float zbq[8] = {qb0.x, qb0.y, qb0.z, qb0.w, qb1.x, qb1.y, qb1.z, qb1.w};

    if (wave == 0) {
        out[IDX_OFF + (size_t)f] = (float)(iA * CSZ + iB);
        const double* zap = za + (size_t)f * 16;
        double s = 0.0;
#pragma unroll
        for (int k = 0; k < 8; ++k) {
            const double d0 = zap[k]     - (double)zaq[k]; s = fma(d0, d0, s);
            const double d1 = zap[8 + k] - (double)zbq[k]; s = fma(d1, d1, s);
        }
#pragma unroll
        for (int off = 32; off > 0; off >>= 1) s += __shfl_down(s, off);
        if (lane == 0) part[fg] = s;
    }

    // ---- output projection (f32), 128 channels per half per wave ----
    const int c0 = wave << 7;
    const size_t obase = ((size_t)b * ND) * NT + t;
    for (int cc = 0; cc < 128; ++cc) {
        const int c = c0 + cc;
        const float* wa = w_out_a + (size_t)c * CDIM;           // uniform -> s_load
        const float* wb = w_out_b + (size_t)c * CDIM;
        float sa = b_out_a[c], sb = b_out_b[c];
#pragma unroll
        for (int k = 0; k < 8; ++k) { sa = fmaf(wa[k], zaq[k], sa); sb = fmaf(wb[k], zbq[k], sb); }
        out[obase + (size_t)c * NT]         = sa;
        out[obase + (size_t)(512 + c) * NT] = sb;
    }
}

__global__ void vq_finalize(const double* __restrict__ part, float* __restrict__ out) {
    const int b = threadIdx.x;
    if (b < NB) {
        double s = 0.0;
        for (int j = 0; j < 64; ++j) s += part[(size_t)b * 64 + j];
        const float v = (float)(s * (1.0 / 32768.0));
        out[CL_OFF + b]  = v;
        out[CBL_OFF + b] = v;
    }
}

// ================= fallback monolith (round-1 proven logic, no ws precompute) =================
__global__ void __launch_bounds__(256, 2)
vq_mono(const float* __restrict__ z,
        const float* __restrict__ w_in_a, const float* __restrict__ b_in_a,
        const float* __restrict__ w_in_b, const float* __restrict__ b_in_b,
        const float* __restrict__ w_out_a, const float* __restrict__ b_out_a,
        const float* __restrict__ w_out_b, const float* __restrict__ b_out_b,
        const float* __restrict__ cb_a, const float* __restrict__ cb_b,
        float* __restrict__ out, double* __restrict__ part) {
    const int tid  = threadIdx.x;
    const int lane = tid & 63;
    const int wave = __builtin_amdgcn_readfirstlane(tid >> 6);
    const int blk  = blockIdx.x;
    const int b    = blk >> 6;
    const int t    = ((blk & 63) << 6) + lane;

    __shared__ double red[4][64][9];
    __shared__ double sBest[2][4][64];
    __shared__ int    sIdx[2][4][64];

    double acc[16];
#pragma unroll
    for (int k = 0; k < 16; ++k) acc[k] = 0.0;
    const float* zp = z + ((size_t)b * ND) * NT + t;
    const int i0 = wave * 256;
#pragma unroll 2
    for (int ii = 0; ii < 256; ++ii) {
        const int i = i0 + ii;
        const double zd = (double)zp[(size_t)i * NT];
#pragma unroll
        for (int o = 0; o < 8; ++o) {
            acc[o]     = fma((double)w_in_a[o * ND + i], zd, acc[o]);
            acc[8 + o] = fma((double)w_in_b[o * ND + i], zd, acc[8 + o]);
        }
    }
    double za[16];
#pragma unroll
    for (int r = 0; r < 2; ++r) {
#pragma unroll
        for (int k = 0; k < 8; ++k) red[wave][lane][k] = acc[8 * r + k];
        __syncthreads();
#pragma unroll
        for (int k = 0; k < 8; ++k)
            za[8*r+k] = ((red[0][lane][k] + red[1][lane][k]) + red[2][lane][k]) + red[3][lane][k];
        __syncthreads();
    }
#pragma unroll
    for (int k = 0; k < 8; ++k) { za[k] += (double)b_in_a[k]; za[8 + k] += (double)b_in_b[k]; }

    if (wave == 0) {
#pragma unroll
        for (int k = 0; k < 16; ++k)
            out[LAT_OFF + ((size_t)b * 16 + k) * NT + t] = (float)za[k];
    }

    double ea[8], eb[8];
    {
        double n2 = 0.0;
#pragma unroll
        for (int k = 0; k < 8; ++k) n2 = fma(za[k], za[k], n2);
        double inv = 1.0 / fmax(sqrt(n2), 1e-12);
#pragma unroll
        for (int k = 0; k < 8; ++k) ea[k] = za[k] * inv;
    }
    {
        double n2 = 0.0;
#pragma unroll
        for (int k = 0; k < 8; ++k) n2 = fma(za[8 + k], za[8 + k], n2);
        double inv = 1.0 / fmax(sqrt(n2), 1e-12);
#pragma unroll
        for (int k = 0; k < 8; ++k) eb[k] = za[8 + k] * inv;
    }

    double bestA = -1e300, bestB = -1e300;
    int ibA = 0, ibB = 0;
    const int j0 = wave << 10;
    for (int jj = 0; jj < 1024; ++jj) {
        const int j = j0 + jj;
        const float* ra = cb_a + (size_t)j * CDIM;
        const float* rb = cb_b + (size_t)j * CDIM;
        double na = 0.0, nb = 0.0, sA = 0.0, sB = 0.0;
#pragma unroll
        for (int k = 0; k < 8; ++k) {
            double av = (double)ra[k], bv2 = (double)rb[k];
            na = fma(av, av, na); nb = fma(bv2, bv2, nb);
            sA = fma(ea[k], av, sA); sB = fma(eb[k], bv2, sB);
        }
        sA /= fmax(sqrt(na), 1e-12);
        sB /= fmax(sqrt(nb), 1e-12);
        if (sA > bestA) { bestA = sA; ibA = j; }
        if (sB > bestB) { bestB = sB; ibB = j; }
    }
    sBest[0][wave][lane] = bestA; sIdx[0][wave][lane] = ibA;
    sBest[1][wave][lane] = bestB; sIdx[1][wave][lane] = ibB;
    __syncthreads();

    double bA = sBest[0][0][lane]; int iA = sIdx[0][0][lane];
    double bB = sBest[1][0][lane]; int iB = sIdx[1][0][lane];
#pragma unroll
    for (int w2 = 1; w2 < 4; ++w2) {
        double d = sBest[0][w2][lane]; int j2 = sIdx[0][w2][lane];
        if (d > bA) { bA = d; iA = j2; }
        d = sBest[1][w2][lane]; j2 = sIdx[1][w2][lane];
        if (d > bB) { bB = d; iB = j2; }
    }

    float4 qa0 = *(const float4*)(cb_a + (size_t)iA * CDIM);
    float4 qa1 = *(const float4*)(cb_a + (size_t)iA * CDIM + 4);
    float4 qb0 = *(const float4*)(cb_b + (size_t)iB * CDIM);
    float4 qb1 = *(const float4*)(cb_b + (size_t)iB * CDIM + 4);
    float zaq[8] = {qa0.x, qa0.y, qa0.z, qa0.w, qa1.x, qa1.y, qa1.z, qa1.w};
    float zbq[8] = {qb0.x, qb0.y, qb0.z, qb0.w, qb1.x, qb1.y, qb1.z, qb1.w};

    if (wave == 0) {
        out[IDX_OFF + (size_t)b * NT + t] = (float)(iA * CSZ + iB);
        double s = 0.0;
#pragma unroll
        for (int k = 0; k < 8; ++k) {
            double d0 = za[k]     - (double)zaq[k]; s = fma(d0, d0, s);
            double d1 = za[8 + k] - (double)zbq[k]; s = fma(d1, d1, s);
        }
#pragma unroll
        for (int off = 32; off > 0; off >>= 1) s += __shfl_down(s, off);
        if (lane == 0) part[blk] = s;
    }

    const int c0 = wave << 7;
    const size_t obase = ((size_t)b * ND) * NT + t;
    for (int cc = 0; cc < 128; ++cc) {
        const int c = c0 + cc;
        const float* wa = w_out_a + (size_t)c * CDIM;
        const float* wb = w_out_b + (size_t)c * CDIM;
        float sa = b_out_a[c], sb = b_out_b[c];
#pragma unroll
        for (int k = 0; k < 8; ++k) { sa = fmaf(wa[k], zaq[k], sa); sb = fmaf(wb[k], zbq[k], sb); }
        out[obase + (size_t)c * NT]         = sa;
        out[obase + (size_t)(512 + c) * NT] = sb;
    }
}

extern "C" void kernel_launch(void* const* d_in, const int* in_sizes, int n_in,
                              void* d_out, int out_size, void* d_ws, size_t ws_size,
                              hipStream_t stream) {
    const float* z       = (const float*)d_in[0];
    const float* w_in_a  = (const float*)d_in[1];
    const float* b_in_a  = (const float*)d_in[2];
    const float* w_in_b  = (const float*)d_in[3];
    const float* b_in_b  = (const float*)d_in[4];
    const float* w_out_a = (const float*)d_in[5];
    const float* b_out_a = (const float*)d_in[6];
    const float* w_out_b = (const float*)d_in[7];
    const float* b_out_b = (const float*)d_in[8];
    const float* cb_a    = (const float*)d_in[9];
    const float* cb_b    = (const float*)d_in[10];
    float* out = (float*)d_out;
    char* ws = (char*)d_ws;

    if (ws_size >= WS_NEED) {
        double* wT     = (double*)(ws + WT_B);
        double* cbn64A = (double*)(ws + CBN64A_B);
        double* cbn64B = (double*)(ws + CBN64B_B);
        float*  cbn32A = (float*) (ws + CBN32A_B);
        float*  cbn32B = (float*) (ws + CBN32B_B);
        double* za     = (double*)(ws + ZA_B);
        float*  e32    = (float*) (ws + E32_B);
        float*  bv     = (float*) (ws + BESTV_B);
        int*    bi     = (int*)   (ws + BESTI_B);
        double* part   = (double*)(ws + PART_B);

        vq_prep<<<96, 256, 0, stream>>>(w_in_a, w_in_b, cb_a, cb_b,
                                        wT, cbn64A, cbn64B, cbn32A, cbn32B);
        vq_proj<<<512, 512, 0, stream>>>(z, b_in_a, b_in_b, wT, za, e32, out);
        vq_scan<<<1024, 256, 0, stream>>>(e32, cbn32A, cbn32B, bv, bi);
        vq_out<<<512, 256, 0, stream>>>(bv, bi, za, cbn64A, cbn64B, cb_a, cb_b,
                                        w_out_a, b_out_a, w_out_b, b_out_b, out, part);
        vq_finalize<<<1, 64, 0, stream>>>(part, out);
    } else {
        double* part = (double*)ws;
        vq_mono<<<512, 256, 0, stream>>>(z, w_in_a, b_in_a, w_in_b, b_in_b,
                                         w_out_a, b_out_a, w_out_b, b_out_b,
                                         cb_a, cb_b, out, part);
        vq_finalize<<<1, 64, 0, stream>>>(part, out);
    }
}